// Round 4
// baseline (323.260 us; speedup 1.0000x reference)
//
#include <hip/hip_runtime.h>

typedef __attribute__((ext_vector_type(8))) __bf16 bf16x8;
typedef __attribute__((ext_vector_type(4))) float f32x4;

#define MAX_ITER_N 20
#define F_TOL_F 1e-6f
#define FREE_NUM_N 64

#define BSZ 1024
#define IN_DIM 512
#define HID 1024
#define OUT_DIM 256
#define M_CON 128
#define NBLK 256

// workspace layout (float offsets)
#define WS_BAR   0                         // 2 uints: counter, generation
#define WS_RES   8                         // 32 uints
#define WS_BP    48                        // 256 f32
#define WS_H1    304                       // 1024x1024 ushort = 524288 floats
#define WS_H2    (WS_H1 + 524288)
#define WS_APC   (WS_H2 + 524288)          // 1024x512 ushort
#define WS_W0C   (WS_APC + 262144)
#define WS_W1C   (WS_W0C + 262144)
#define WS_W2C   (WS_W1C + 524288)
#define WS_WZG   (WS_W2C + 131072)
#define WS_AG    (WS_WZG + 32768)

__device__ __forceinline__ unsigned short f2bf(float f) {
    unsigned int u = __float_as_uint(f);
    u += 0x7fffu + ((u >> 16) & 1u);
    return (unsigned short)(u >> 16);
}

__device__ __forceinline__ void gload_lds16(const unsigned short* g, unsigned short* l) {
    __builtin_amdgcn_global_load_lds(
        (const __attribute__((address_space(1))) unsigned int*)(const void*)g,
        (__attribute__((address_space(3))) unsigned int*)(void*)l, 16, 0, 0);
}

// device-scope grid barrier; all NBLK blocks co-resident by capacity
// (__launch_bounds__(256): 4 waves/block over 4 SIMDs -> every CU fits >=1 block).
__device__ __forceinline__ void grid_barrier(unsigned int* bar) {
    __syncthreads();
    if (threadIdx.x == 0) {
        unsigned int g = __hip_atomic_load(&bar[1], __ATOMIC_RELAXED, __HIP_MEMORY_SCOPE_AGENT);
        unsigned int a = __hip_atomic_fetch_add(&bar[0], 1u, __ATOMIC_ACQ_REL, __HIP_MEMORY_SCOPE_AGENT);
        if (a == (unsigned int)(NBLK - 1)) {
            __hip_atomic_store(&bar[0], 0u, __ATOMIC_RELAXED, __HIP_MEMORY_SCOPE_AGENT);
            __hip_atomic_store(&bar[1], g + 1u, __ATOMIC_RELEASE, __HIP_MEMORY_SCOPE_AGENT);
        } else {
            while (__hip_atomic_load(&bar[1], __ATOMIC_ACQUIRE, __HIP_MEMORY_SCOPE_AGENT) == g)
                __builtin_amdgcn_s_sleep(2);
        }
    }
    __syncthreads();
}

// ---- GEMM tile helpers (verified in R3: XOR-swizzled granules, lane-linear LDS dest) ----
__device__ __forceinline__ void stage_tile(const unsigned short* __restrict__ src,
                                           unsigned short* lds, int ldK, int w, int lane) {
#pragma unroll
    for (int i = 0; i < 2; ++i) {
        int gbase = i * 256 + w * 64;          // wave-uniform granule base
        int g = gbase + lane;
        int row = g >> 3;
        int sgc = (g & 7) ^ (row & 7);         // permuted global granule
        gload_lds16(src + row * ldK + sgc * 8, lds + gbase * 8);
    }
}

__device__ __forceinline__ bf16x8 frag_ld(const unsigned short* lds, int row, int j) {
    int phys = j ^ (row & 7);
    return __builtin_bit_cast(bf16x8, *(const uint4*)(lds + row * 64 + phys * 8));
}

template<bool RELU, bool F32OUT>
__device__ void gemm_dev(const unsigned short* __restrict__ A,
                         const unsigned short* __restrict__ B,
                         const float* __restrict__ bias, void* __restrict__ Cv,
                         int N_, int K, int tilesN, int ntiles,
                         unsigned short* As, unsigned short* Bs)
{
    const int tile = blockIdx.x;
    if (tile >= ntiles) return;
    const int tid = threadIdx.x;
    const int w = tid >> 6;
    const int lane = tid & 63;
    const int ln = lane & 15;
    const int q  = lane >> 4;
    const int row0 = (tile / tilesN) * 64;
    const int col0 = (tile % tilesN) * 64;
    const unsigned short* Ab = A + row0 * K;
    const unsigned short* Bb = B + col0 * K;

    f32x4 acc[2][2];
#pragma unroll
    for (int rt = 0; rt < 2; ++rt)
#pragma unroll
        for (int ct = 0; ct < 2; ++ct)
            acc[rt][ct] = (f32x4){0.f, 0.f, 0.f, 0.f};

    for (int k0 = 0; k0 < K; k0 += 64) {
        stage_tile(Ab + k0, As, K, w, lane);
        stage_tile(Bb + k0, Bs, K, w, lane);
        __syncthreads();
#pragma unroll
        for (int ks = 0; ks < 2; ++ks) {
            bf16x8 af[2], bfv[2];
#pragma unroll
            for (int rt = 0; rt < 2; ++rt)
                af[rt] = frag_ld(As, (w >> 1) * 32 + rt * 16 + ln, ks * 4 + q);
#pragma unroll
            for (int ct = 0; ct < 2; ++ct)
                bfv[ct] = frag_ld(Bs, (w & 1) * 32 + ct * 16 + ln, ks * 4 + q);
#pragma unroll
            for (int rt = 0; rt < 2; ++rt)
#pragma unroll
                for (int ct = 0; ct < 2; ++ct)
                    acc[rt][ct] = __builtin_amdgcn_mfma_f32_16x16x32_bf16(
                        af[rt], bfv[ct], acc[rt][ct], 0, 0, 0);
        }
        __syncthreads();
    }

    float bv[2];
#pragma unroll
    for (int ct = 0; ct < 2; ++ct)
        bv[ct] = bias[col0 + (w & 1) * 32 + ct * 16 + ln];
#pragma unroll
    for (int rt = 0; rt < 2; ++rt)
#pragma unroll
        for (int ct = 0; ct < 2; ++ct) {
            int c = col0 + (w & 1) * 32 + ct * 16 + ln;
#pragma unroll
            for (int i = 0; i < 4; ++i) {
                int r = row0 + (w >> 1) * 32 + rt * 16 + q * 4 + i;
                float v = acc[rt][ct][i] + bv[ct];
                if (RELU) v = fmaxf(v, 0.0f);
                if (F32OUT) ((float*)Cv)[r * N_ + c] = v;
                else ((unsigned short*)Cv)[r * N_ + c] = f2bf(v);
            }
        }
}

// ---- the single persistent kernel ----
__global__ __launch_bounds__(256, 1) void mega_k(
    const float* __restrict__ b_primal, const float* __restrict__ W0,
    const float* __restrict__ b0, const float* __restrict__ W1,
    const float* __restrict__ b1, const float* __restrict__ W2,
    const float* __restrict__ b2, const float* __restrict__ Amat,
    const float* __restrict__ b_vec, const float* __restrict__ WzProj,
    const float* __restrict__ WbProj, float* __restrict__ out,
    float* __restrict__ ws)
{
    __shared__ __align__(16) unsigned char smem[64 * 64 * 2 * 2 + 256];
    unsigned short* As = (unsigned short*)smem;
    unsigned short* Bs = As + 64 * 64;

    unsigned int* bar = (unsigned int*)(ws + WS_BAR);
    unsigned int* res = (unsigned int*)(ws + WS_RES);
    float* bp = ws + WS_BP;
    unsigned short* h1c = (unsigned short*)(ws + WS_H1);
    unsigned short* h2c = (unsigned short*)(ws + WS_H2);
    unsigned short* APc = (unsigned short*)(ws + WS_APC);
    unsigned short* W0c = (unsigned short*)(ws + WS_W0C);
    unsigned short* W1c = (unsigned short*)(ws + WS_W1C);
    unsigned short* W2c = (unsigned short*)(ws + WS_W2C);
    unsigned short* WzG = (unsigned short*)(ws + WS_WZG);
    unsigned short* AG  = (unsigned short*)(ws + WS_AG);
    float* outz = out + BSZ * OUT_DIM;   // MLP output chunk (z_0)

    const int tid = threadIdx.x;

    // ---- phase 0: bf16 conversion (2400 x 1024-elem tiles) + bias_proj ----
    for (int u = blockIdx.x; u <= 2400; u += NBLK) {
        if (u == 2400) {
            float s = 0.0f;
            for (int k = 0; k < M_CON; ++k) s += b_vec[k] * WbProj[tid * M_CON + k];
            bp[tid] = s;
            continue;
        }
        const float* src; unsigned short* dst; int off;
        if (u < 512)       { src = b_primal; dst = APc; off = u; }
        else if (u < 1024) { src = W0; dst = W0c; off = u - 512; }
        else if (u < 2048) { src = W1; dst = W1c; off = u - 1024; }
        else if (u < 2304) { src = W2; dst = W2c; off = u - 2048; }
        else if (u < 2368) { src = WzProj; dst = WzG; off = u - 2304; }
        else               { src = Amat; dst = AG;  off = u - 2368; }
        int idx = off * 1024 + tid * 4;
        float4 v = *(const float4*)(src + idx);
        ushort4 o;
        o.x = f2bf(v.x); o.y = f2bf(v.y); o.z = f2bf(v.z); o.w = f2bf(v.w);
        *(ushort4*)(dst + idx) = o;
    }
    grid_barrier(bar);

    // ---- phase A/B/C: the three MLP GEMMs ----
    gemm_dev<true, false>(APc, W0c, b0, (void*)h1c, HID, IN_DIM, 16, 256, As, Bs);
    grid_barrier(bar);
    gemm_dev<true, false>(h1c, W1c, b1, (void*)h2c, HID, HID, 16, 256, As, Bs);
    grid_barrier(bar);
    gemm_dev<false, true>(h2c, W2c, b2, (void*)outz, OUT_DIM, HID, 4, 64, As, Bs);
    grid_barrier(bar);

    // ---- phase D: 20-iteration fixed-point loop (blocks 0..63) ----
    if (blockIdx.x < 64) {
        unsigned short (*zS)[264] = (unsigned short(*)[264])smem;
        float* red = (float*)(smem + 16 * 264 * 2);

        const int wave = tid >> 6;
        const int lane = tid & 63;
        const int ln   = lane & 15;
        const int q    = lane >> 4;
        const int r0   = blockIdx.x * 16;

        {
            int row = tid >> 4;
            int c0  = (tid & 15) * 16;
            const float* src = outz + (r0 + row) * OUT_DIM + c0;
#pragma unroll
            for (int i = 0; i < 16; ++i) zS[row][c0 + i] = f2bf(src[i]);
        }

        bf16x8 afr[2][8];
        float bvv[2];
#pragma unroll
        for (int mt = 0; mt < 2; ++mt) {
            int m = wave * 32 + mt * 16 + ln;
            bvv[mt] = b_vec[m];
#pragma unroll
            for (int ks = 0; ks < 8; ++ks)
                afr[mt][ks] = __builtin_bit_cast(bf16x8, *(const uint4*)(AG + m * OUT_DIM + ks * 32 + q * 8));
        }
        int colg[4];
        float bpv[4];
        bf16x8 wzfr[4][8];
#pragma unroll
        for (int nt = 0; nt < 4; ++nt) {
            colg[nt] = wave * 64 + nt * 16 + ln;
            bpv[nt]  = bp[colg[nt]];
#pragma unroll
            for (int ks = 0; ks < 8; ++ks)
                wzfr[nt][ks] = __builtin_bit_cast(bf16x8, *(const uint4*)(WzG + colg[nt] * OUT_DIM + ks * 32 + q * 8));
        }
        __syncthreads();

        bf16x8 zfr[8];
#pragma unroll
        for (int ks = 0; ks < 8; ++ks)
            zfr[ks] = __builtin_bit_cast(bf16x8, *(const uint4*)&zS[ln][ks * 32 + q * 8]);

        const f32x4 zero4 = {0.f, 0.f, 0.f, 0.f};

        for (int t = 1; t <= MAX_ITER_N; ++t) {
            f32x4 acc[4];
#pragma unroll
            for (int nt = 0; nt < 4; ++nt) acc[nt] = zero4;
#pragma unroll
            for (int ks = 0; ks < 8; ++ks)
#pragma unroll
                for (int nt = 0; nt < 4; ++nt)
                    acc[nt] = __builtin_amdgcn_mfma_f32_16x16x32_bf16(zfr[ks], wzfr[nt][ks], acc[nt], 0, 0, 0);
            float vals[4][4];
#pragma unroll
            for (int nt = 0; nt < 4; ++nt)
#pragma unroll
                for (int i = 0; i < 4; ++i) {
                    float v = acc[nt][i] + bpv[nt];
                    if (colg[nt] >= FREE_NUM_N) v = fmaxf(v, 0.0f);
                    vals[nt][i] = v;
                }
            if (t == MAX_ITER_N) {
#pragma unroll
                for (int nt = 0; nt < 4; ++nt)
#pragma unroll
                    for (int i = 0; i < 4; ++i)
                        out[(r0 + q * 4 + i) * OUT_DIM + colg[nt]] = vals[nt][i];
            }
            __syncthreads();   // S1: all waves done reading zS (z_{t-1})
#pragma unroll
            for (int nt = 0; nt < 4; ++nt)
#pragma unroll
                for (int i = 0; i < 4; ++i)
                    zS[q * 4 + i][colg[nt]] = f2bf(vals[nt][i]);
            __syncthreads();   // S2: zS = z_t complete
#pragma unroll
            for (int ks = 0; ks < 8; ++ks)
                zfr[ks] = __builtin_bit_cast(bf16x8, *(const uint4*)&zS[ln][ks * 32 + q * 8]);

            f32x4 acc2[2];
            acc2[0] = zero4; acc2[1] = zero4;
#pragma unroll
            for (int ks = 0; ks < 8; ++ks)
#pragma unroll
                for (int mt = 0; mt < 2; ++mt)
                    acc2[mt] = __builtin_amdgcn_mfma_f32_16x16x32_bf16(zfr[ks], afr[mt][ks], acc2[mt], 0, 0, 0);
            float lmax = 0.0f;
#pragma unroll
            for (int mt = 0; mt < 2; ++mt)
#pragma unroll
                for (int i = 0; i < 4; ++i)
                    lmax = fmaxf(lmax, fabsf(acc2[mt][i] - bvv[mt]));
#pragma unroll
            for (int off = 32; off > 0; off >>= 1)
                lmax = fmaxf(lmax, __shfl_xor(lmax, off));
            if (lane == 0) red[wave] = lmax;
            __syncthreads();   // S3
            if (tid == 0) {
                float bm = fmaxf(fmaxf(red[0], red[1]), fmaxf(red[2], red[3]));
                atomicMax(res + (t - 1), __float_as_uint(bm));
            }
        }
    }
    grid_barrier(bar);

    // ---- phase E: replay the reference stopping rule; cold fp32 fallback ----
    int T = MAX_ITER_N;
    for (int t = 0; t < MAX_ITER_N; ++t) {
        float r = __uint_as_float(res[t]);
        if (!(r > F_TOL_F)) { T = t + 1; break; }   // covers res<=tol and NaN
    }
    if (blockIdx.x == 0 && tid == 0)
        out[2 * BSZ * OUT_DIM] = (float)(T + 1);    // curr_iter

    if (T < MAX_ITER_N && blockIdx.x < 64) {        // cold path: exact fp32 recompute
        float (*zF)[257] = (float(*)[257])smem;
        const int r0 = blockIdx.x * 16;
        const int row = tid >> 4;
        const int c0 = (tid & 15) * 16;
        for (int i = 0; i < 16; ++i) zF[row][c0 + i] = outz[(r0 + row) * OUT_DIM + c0 + i];
        __syncthreads();
        const int j = tid;
        const float bj = bp[j];
        for (int t = 0; t < T; ++t) {
            float acc[16] = {};
            for (int k = 0; k < OUT_DIM; ++k) {
                float w = WzProj[j * OUT_DIM + k];
#pragma unroll
                for (int r = 0; r < 16; ++r) acc[r] += zF[r][k] * w;
            }
            __syncthreads();
#pragma unroll
            for (int r = 0; r < 16; ++r) {
                float v = acc[r] + bj;
                if (j >= FREE_NUM_N) v = fmaxf(v, 0.0f);
                zF[r][j] = v;
            }
            __syncthreads();
        }
        for (int i = 0; i < 16; ++i) out[(r0 + row) * OUT_DIM + c0 + i] = zF[row][c0 + i];
    }
}

extern "C" void kernel_launch(void* const* d_in, const int* in_sizes, int n_in,
                              void* d_out, int out_size, void* d_ws, size_t ws_size,
                              hipStream_t stream) {
    const float* b_primal = (const float*)d_in[0];
    const float* W0     = (const float*)d_in[1];
    const float* b0     = (const float*)d_in[2];
    const float* W1     = (const float*)d_in[3];
    const float* b1     = (const float*)d_in[4];
    const float* W2     = (const float*)d_in[5];
    const float* b2     = (const float*)d_in[6];
    const float* Amat   = (const float*)d_in[7];
    const float* b_vec  = (const float*)d_in[8];
    const float* WzProj = (const float*)d_in[9];
    const float* WbProj = (const float*)d_in[10];
    float* out = (float*)d_out;
    float* ws  = (float*)d_ws;

    // zero barrier state + res slots (ws is poisoned 0xAA before every call)
    hipMemsetAsync(ws, 0, (WS_BP) * sizeof(float), stream);

    hipLaunchKernelGGL(mega_k, dim3(NBLK), dim3(256), 0, stream,
                       b_primal, W0, b0, W1, b1, W2, b2, Amat, b_vec,
                       WzProj, WbProj, out, ws);
}

// Round 5
// 227.616 us; speedup vs baseline: 1.4202x; 1.4202x over previous
//
#include <hip/hip_runtime.h>

typedef __attribute__((ext_vector_type(8))) __bf16 bf16x8;
typedef __attribute__((ext_vector_type(4))) float f32x4;

#define MAX_ITER_N 20
#define F_TOL_F 1e-6f
#define FREE_NUM_N 64

#define BSZ 1024
#define IN_DIM 512
#define HID 1024
#define OUT_DIM 256
#define M_CON 128
#define NBLK1 256
#define NBLK2 64

// workspace layout (float offsets)
#define WS_BAR   0                         // 4 uints: K1 {cnt,gen}, K2 {cnt,gen}
#define WS_RES   8                         // 32 uints
#define WS_BP    48                        // 256 f32
#define WS_H1    304
#define WS_H2    (WS_H1 + 524288)
#define WS_APC   (WS_H2 + 524288)
#define WS_W0C   (WS_APC + 262144)
#define WS_W1C   (WS_W0C + 262144)
#define WS_W2C   (WS_W1C + 524288)
#define WS_WZG   (WS_W2C + 131072)
#define WS_AG    (WS_WZG + 32768)

__device__ __forceinline__ unsigned short f2bf(float f) {
    unsigned int u = __float_as_uint(f);
    u += 0x7fffu + ((u >> 16) & 1u);
    return (unsigned short)(u >> 16);
}

__device__ __forceinline__ void gload_lds16(const unsigned short* g, unsigned short* l) {
    __builtin_amdgcn_global_load_lds(
        (const __attribute__((address_space(1))) unsigned int*)(const void*)g,
        (__attribute__((address_space(3))) unsigned int*)(void*)l, 16, 0, 0);
}

// device-scope grid barrier (all nblk blocks co-resident by capacity)
__device__ __forceinline__ void grid_barrier(unsigned int* bar, unsigned int nblk) {
    __syncthreads();
    if (threadIdx.x == 0) {
        unsigned int g = __hip_atomic_load(&bar[1], __ATOMIC_RELAXED, __HIP_MEMORY_SCOPE_AGENT);
        unsigned int a = __hip_atomic_fetch_add(&bar[0], 1u, __ATOMIC_ACQ_REL, __HIP_MEMORY_SCOPE_AGENT);
        if (a == nblk - 1u) {
            __hip_atomic_store(&bar[0], 0u, __ATOMIC_RELAXED, __HIP_MEMORY_SCOPE_AGENT);
            __hip_atomic_store(&bar[1], g + 1u, __ATOMIC_RELEASE, __HIP_MEMORY_SCOPE_AGENT);
        } else {
            while (__hip_atomic_load(&bar[1], __ATOMIC_ACQUIRE, __HIP_MEMORY_SCOPE_AGENT) == g)
                __builtin_amdgcn_s_sleep(2);
        }
    }
    __syncthreads();
}

__device__ __forceinline__ bf16x8 frag_ld(const unsigned short* lds, int row, int j) {
    int phys = j ^ (row & 7);
    return __builtin_bit_cast(bf16x8, *(const uint4*)(lds + row * 64 + phys * 8));
}

// 512-thread GEMM tile: 64x64, BK=64, 8 waves (2 row-groups x 4 col-groups)
template<bool RELU, bool F32OUT>
__device__ void gemm_dev512(const unsigned short* __restrict__ A,
                            const unsigned short* __restrict__ B,
                            const float* __restrict__ bias, void* __restrict__ Cv,
                            int N_, int K, int tilesN, int ntiles,
                            unsigned short* As, unsigned short* Bs)
{
    const int tile = blockIdx.x;
    if (tile >= ntiles) return;
    const int tid = threadIdx.x;
    const int w = tid >> 6;       // 0..7
    const int lane = tid & 63;
    const int ln = lane & 15;
    const int q  = lane >> 4;
    const int wr = w >> 2;        // 0..1 (row group of 32)
    const int wc = w & 3;         // 0..3 (col group of 16)
    const int row0 = (tile / tilesN) * 64;
    const int col0 = (tile % tilesN) * 64;
    const unsigned short* Ab = A + row0 * K;
    const unsigned short* Bb = B + col0 * K;

    // staging granule: wave-uniform base w*64, lane granule g
    const int g = w * 64 + lane;
    const int srow = g >> 3;
    const int sgc = (g & 7) ^ (srow & 7);   // XOR-permuted global granule
    const int soff = srow * K + sgc * 8;
    unsigned short* aDst = As + w * 64 * 8;
    unsigned short* bDst = Bs + w * 64 * 8;

    f32x4 acc[2];
    acc[0] = (f32x4){0.f, 0.f, 0.f, 0.f};
    acc[1] = (f32x4){0.f, 0.f, 0.f, 0.f};

    for (int k0 = 0; k0 < K; k0 += 64) {
        gload_lds16(Ab + k0 + soff, aDst);
        gload_lds16(Bb + k0 + soff, bDst);
        __syncthreads();
#pragma unroll
        for (int ks = 0; ks < 2; ++ks) {
            int j = ks * 4 + q;
            bf16x8 af[2];
            af[0] = frag_ld(As, wr * 32 + ln, j);
            af[1] = frag_ld(As, wr * 32 + 16 + ln, j);
            bf16x8 bf = frag_ld(Bs, wc * 16 + ln, j);
            acc[0] = __builtin_amdgcn_mfma_f32_16x16x32_bf16(af[0], bf, acc[0], 0, 0, 0);
            acc[1] = __builtin_amdgcn_mfma_f32_16x16x32_bf16(af[1], bf, acc[1], 0, 0, 0);
        }
        __syncthreads();
    }

    const int c = col0 + wc * 16 + ln;
    const float bv = bias[c];
#pragma unroll
    for (int rt = 0; rt < 2; ++rt)
#pragma unroll
        for (int i = 0; i < 4; ++i) {
            int r = row0 + wr * 32 + rt * 16 + q * 4 + i;
            float v = acc[rt][i] + bv;
            if (RELU) v = fmaxf(v, 0.0f);
            if (F32OUT) ((float*)Cv)[r * N_ + c] = v;
            else ((unsigned short*)Cv)[r * N_ + c] = f2bf(v);
        }
}

// ---- K1: conversions + 3 MLP GEMMs, grid-barriered; register-light ----
__global__ __launch_bounds__(512, 2) void front_k(
    const float* __restrict__ b_primal, const float* __restrict__ W0,
    const float* __restrict__ b0, const float* __restrict__ W1,
    const float* __restrict__ b1, const float* __restrict__ W2,
    const float* __restrict__ b2, const float* __restrict__ Amat,
    const float* __restrict__ b_vec, const float* __restrict__ WzProj,
    const float* __restrict__ WbProj, float* __restrict__ out,
    float* __restrict__ ws)
{
    __shared__ __align__(16) unsigned short As[64 * 64];
    __shared__ __align__(16) unsigned short Bs[64 * 64];

    unsigned int* bar = (unsigned int*)(ws + WS_BAR);
    float* bp = ws + WS_BP;
    unsigned short* h1c = (unsigned short*)(ws + WS_H1);
    unsigned short* h2c = (unsigned short*)(ws + WS_H2);
    unsigned short* APc = (unsigned short*)(ws + WS_APC);
    unsigned short* W0c = (unsigned short*)(ws + WS_W0C);
    unsigned short* W1c = (unsigned short*)(ws + WS_W1C);
    unsigned short* W2c = (unsigned short*)(ws + WS_W2C);
    unsigned short* WzG = (unsigned short*)(ws + WS_WZG);
    unsigned short* AG  = (unsigned short*)(ws + WS_AG);
    float* outz = out + BSZ * OUT_DIM;

    const int tid = threadIdx.x;

    // phase 0: bf16 conversion in 2048-elem units + bias_proj (unit 1200)
    for (int u = blockIdx.x; u <= 1200; u += NBLK1) {
        if (u == 1200) {
            if (tid < 256) {
                float s = 0.0f;
                for (int k = 0; k < M_CON; ++k) s += b_vec[k] * WbProj[tid * M_CON + k];
                bp[tid] = s;
            }
            continue;
        }
        const float* src; unsigned short* dst; int off;
        if (u < 256)       { src = b_primal; dst = APc; off = u; }
        else if (u < 512)  { src = W0; dst = W0c; off = u - 256; }
        else if (u < 1024) { src = W1; dst = W1c; off = u - 512; }
        else if (u < 1152) { src = W2; dst = W2c; off = u - 1024; }
        else if (u < 1184) { src = WzProj; dst = WzG; off = u - 1152; }
        else               { src = Amat; dst = AG;  off = u - 1184; }
        int idx = off * 2048 + tid * 4;
        float4 v = *(const float4*)(src + idx);
        ushort4 o;
        o.x = f2bf(v.x); o.y = f2bf(v.y); o.z = f2bf(v.z); o.w = f2bf(v.w);
        *(ushort4*)(dst + idx) = o;
    }
    grid_barrier(bar, NBLK1);

    gemm_dev512<true, false>(APc, W0c, b0, (void*)h1c, HID, IN_DIM, 16, 256, As, Bs);
    grid_barrier(bar, NBLK1);
    gemm_dev512<true, false>(h1c, W1c, b1, (void*)h2c, HID, HID, 16, 256, As, Bs);
    grid_barrier(bar, NBLK1);
    gemm_dev512<false, true>(h2c, W2c, b2, (void*)outz, OUT_DIM, HID, 4, 64, As, Bs);
}

// ---- K2: 20-iter fixed-point loop + decide + cold fallback; register-heavy ----
__global__ __launch_bounds__(256, 1) void loop_k(
    const float* __restrict__ Amat_f32_unused,
    const float* __restrict__ b_vec,
    const float* __restrict__ WzProj,
    float* __restrict__ out, float* __restrict__ ws)
{
    __shared__ __align__(16) unsigned char smem[16 * 264 * 2 + 256];
    unsigned int* bar2 = (unsigned int*)(ws + WS_BAR) + 2;
    unsigned int* res = (unsigned int*)(ws + WS_RES);
    float* bp = ws + WS_BP;
    const unsigned short* WzG = (const unsigned short*)(ws + WS_WZG);
    const unsigned short* AG  = (const unsigned short*)(ws + WS_AG);
    float* outz = out + BSZ * OUT_DIM;

    const int tid  = threadIdx.x;
    const int wave = tid >> 6;
    const int lane = tid & 63;
    const int ln   = lane & 15;
    const int q    = lane >> 4;
    const int r0   = blockIdx.x * 16;

    {
        unsigned short (*zS)[264] = (unsigned short(*)[264])smem;
        float* red = (float*)(smem + 16 * 264 * 2);

        {
            int row = tid >> 4;
            int c0  = (tid & 15) * 16;
            const float* src = outz + (r0 + row) * OUT_DIM + c0;
#pragma unroll
            for (int i = 0; i < 16; ++i) zS[row][c0 + i] = f2bf(src[i]);
        }

        bf16x8 afr[2][8];
        float bvv[2];
#pragma unroll
        for (int mt = 0; mt < 2; ++mt) {
            int m = wave * 32 + mt * 16 + ln;
            bvv[mt] = b_vec[m];
#pragma unroll
            for (int ks = 0; ks < 8; ++ks)
                afr[mt][ks] = __builtin_bit_cast(bf16x8, *(const uint4*)(AG + m * OUT_DIM + ks * 32 + q * 8));
        }
        int colg[4];
        float bpv[4];
        bf16x8 wzfr[4][8];
#pragma unroll
        for (int nt = 0; nt < 4; ++nt) {
            colg[nt] = wave * 64 + nt * 16 + ln;
            bpv[nt]  = bp[colg[nt]];
#pragma unroll
            for (int ks = 0; ks < 8; ++ks)
                wzfr[nt][ks] = __builtin_bit_cast(bf16x8, *(const uint4*)(WzG + colg[nt] * OUT_DIM + ks * 32 + q * 8));
        }
        __syncthreads();

        bf16x8 zfr[8];
#pragma unroll
        for (int ks = 0; ks < 8; ++ks)
            zfr[ks] = __builtin_bit_cast(bf16x8, *(const uint4*)&zS[ln][ks * 32 + q * 8]);

        const f32x4 zero4 = {0.f, 0.f, 0.f, 0.f};

        for (int t = 1; t <= MAX_ITER_N; ++t) {
            f32x4 acc[4];
#pragma unroll
            for (int nt = 0; nt < 4; ++nt) acc[nt] = zero4;
#pragma unroll
            for (int ks = 0; ks < 8; ++ks)
#pragma unroll
                for (int nt = 0; nt < 4; ++nt)
                    acc[nt] = __builtin_amdgcn_mfma_f32_16x16x32_bf16(zfr[ks], wzfr[nt][ks], acc[nt], 0, 0, 0);
            float vals[4][4];
#pragma unroll
            for (int nt = 0; nt < 4; ++nt)
#pragma unroll
                for (int i = 0; i < 4; ++i) {
                    float v = acc[nt][i] + bpv[nt];
                    if (colg[nt] >= FREE_NUM_N) v = fmaxf(v, 0.0f);
                    vals[nt][i] = v;
                }
            if (t == MAX_ITER_N) {
#pragma unroll
                for (int nt = 0; nt < 4; ++nt)
#pragma unroll
                    for (int i = 0; i < 4; ++i)
                        out[(r0 + q * 4 + i) * OUT_DIM + colg[nt]] = vals[nt][i];
            }
            __syncthreads();   // S1: all waves done reading zS (z_{t-1})
#pragma unroll
            for (int nt = 0; nt < 4; ++nt)
#pragma unroll
                for (int i = 0; i < 4; ++i)
                    zS[q * 4 + i][colg[nt]] = f2bf(vals[nt][i]);
            __syncthreads();   // S2: zS = z_t complete
#pragma unroll
            for (int ks = 0; ks < 8; ++ks)
                zfr[ks] = __builtin_bit_cast(bf16x8, *(const uint4*)&zS[ln][ks * 32 + q * 8]);

            f32x4 acc2[2];
            acc2[0] = zero4; acc2[1] = zero4;
#pragma unroll
            for (int ks = 0; ks < 8; ++ks)
#pragma unroll
                for (int mt = 0; mt < 2; ++mt)
                    acc2[mt] = __builtin_amdgcn_mfma_f32_16x16x32_bf16(zfr[ks], afr[mt][ks], acc2[mt], 0, 0, 0);
            float lmax = 0.0f;
#pragma unroll
            for (int mt = 0; mt < 2; ++mt)
#pragma unroll
                for (int i = 0; i < 4; ++i)
                    lmax = fmaxf(lmax, fabsf(acc2[mt][i] - bvv[mt]));
#pragma unroll
            for (int off = 32; off > 0; off >>= 1)
                lmax = fmaxf(lmax, __shfl_xor(lmax, off));
            if (lane == 0) red[wave] = lmax;
            __syncthreads();   // S3
            if (tid == 0) {
                float bm = fmaxf(fmaxf(red[0], red[1]), fmaxf(red[2], red[3]));
                atomicMax(res + (t - 1), __float_as_uint(bm));
            }
        }
    }
    grid_barrier(bar2, NBLK2);

    // decide (replay reference stopping rule) + cold fp32 fallback
    int T = MAX_ITER_N;
    for (int t = 0; t < MAX_ITER_N; ++t) {
        float r = __uint_as_float(res[t]);
        if (!(r > F_TOL_F)) { T = t + 1; break; }   // covers res<=tol and NaN
    }
    if (blockIdx.x == 0 && tid == 0)
        out[2 * BSZ * OUT_DIM] = (float)(T + 1);    // curr_iter

    if (T < MAX_ITER_N) {                           // cold path: exact fp32 recompute
        float (*zF)[257] = (float(*)[257])smem;
        const int row = tid >> 4;
        const int c0 = (tid & 15) * 16;
        for (int i = 0; i < 16; ++i) zF[row][c0 + i] = outz[(r0 + row) * OUT_DIM + c0 + i];
        __syncthreads();
        const int j = tid;
        const float bj = bp[j];
        for (int t = 0; t < T; ++t) {
            float acc[16] = {};
            for (int k = 0; k < OUT_DIM; ++k) {
                float w = WzProj[j * OUT_DIM + k];
#pragma unroll
                for (int r = 0; r < 16; ++r) acc[r] += zF[r][k] * w;
            }
            __syncthreads();
#pragma unroll
            for (int r = 0; r < 16; ++r) {
                float v = acc[r] + bj;
                if (j >= FREE_NUM_N) v = fmaxf(v, 0.0f);
                zF[r][j] = v;
            }
            __syncthreads();
        }
        for (int i = 0; i < 16; ++i) out[(r0 + row) * OUT_DIM + c0 + i] = zF[row][c0 + i];
    }
}

extern "C" void kernel_launch(void* const* d_in, const int* in_sizes, int n_in,
                              void* d_out, int out_size, void* d_ws, size_t ws_size,
                              hipStream_t stream) {
    const float* b_primal = (const float*)d_in[0];
    const float* W0     = (const float*)d_in[1];
    const float* b0     = (const float*)d_in[2];
    const float* W1     = (const float*)d_in[3];
    const float* b1     = (const float*)d_in[4];
    const float* W2     = (const float*)d_in[5];
    const float* b2     = (const float*)d_in[6];
    const float* Amat   = (const float*)d_in[7];
    const float* b_vec  = (const float*)d_in[8];
    const float* WzProj = (const float*)d_in[9];
    const float* WbProj = (const float*)d_in[10];
    float* out = (float*)d_out;
    float* ws  = (float*)d_ws;

    // zero barriers + res (ws is poisoned 0xAA before every call)
    hipMemsetAsync(ws, 0, WS_BP * sizeof(float), stream);

    hipLaunchKernelGGL(front_k, dim3(NBLK1), dim3(512), 0, stream,
                       b_primal, W0, b0, W1, b1, W2, b2, Amat, b_vec,
                       WzProj, WbProj, out, ws);
    hipLaunchKernelGGL(loop_k, dim3(NBLK2), dim3(256), 0, stream,
                       Amat, b_vec, WzProj, out, ws);
}

// Round 6
// 140.161 us; speedup vs baseline: 2.3064x; 1.6240x over previous
//
#include <hip/hip_runtime.h>

typedef __attribute__((ext_vector_type(8))) __bf16 bf16x8;
typedef __attribute__((ext_vector_type(4))) float f32x4;

#define MAX_ITER_N 20
#define F_TOL_F 1e-6f
#define FREE_NUM_N 64

#define BSZ 1024
#define IN_DIM 512
#define HID 1024
#define OUT_DIM 256
#define M_CON 128

// workspace layout (float offsets)
#define WS_BAR   0                         // (unused now, kept for memset span)
#define WS_RES   8                         // 32 uints
#define WS_BP    48                        // 256 f32
#define WS_H1    304
#define WS_H2    (WS_H1 + 524288)
#define WS_APC   (WS_H2 + 524288)
#define WS_W0C   (WS_APC + 262144)
#define WS_W1C   (WS_W0C + 262144)
#define WS_W2C   (WS_W1C + 524288)
#define WS_WZG   (WS_W2C + 131072)
#define WS_AG    (WS_WZG + 32768)

__device__ __forceinline__ unsigned short f2bf(float f) {
    unsigned int u = __float_as_uint(f);
    u += 0x7fffu + ((u >> 16) & 1u);
    return (unsigned short)(u >> 16);
}

__device__ __forceinline__ void gload_lds16(const unsigned short* g, unsigned short* l) {
    __builtin_amdgcn_global_load_lds(
        (const __attribute__((address_space(1))) unsigned int*)(const void*)g,
        (__attribute__((address_space(3))) unsigned int*)(void*)l, 16, 0, 0);
}

// ---- prep: all bf16 conversions + bias_proj; 2401 blocks x 256 ----
__global__ __launch_bounds__(256) void prep_k(
    const float* __restrict__ b_primal, const float* __restrict__ W0,
    const float* __restrict__ W1, const float* __restrict__ W2,
    const float* __restrict__ Wz, const float* __restrict__ Am,
    const float* __restrict__ b_vec, const float* __restrict__ WbProj,
    float* __restrict__ ws)
{
    unsigned short* APc = (unsigned short*)(ws + WS_APC);
    unsigned short* W0c = (unsigned short*)(ws + WS_W0C);
    unsigned short* W1c = (unsigned short*)(ws + WS_W1C);
    unsigned short* W2c = (unsigned short*)(ws + WS_W2C);
    unsigned short* WzG = (unsigned short*)(ws + WS_WZG);
    unsigned short* AG  = (unsigned short*)(ws + WS_AG);
    float* bp = ws + WS_BP;

    int b = blockIdx.x;
    int tid = threadIdx.x;
    if (b >= 2400) {
        float s = 0.0f;
        for (int k = 0; k < M_CON; ++k) s += b_vec[k] * WbProj[tid * M_CON + k];
        bp[tid] = s;
        return;
    }
    const float* src; unsigned short* dst; int off;
    if (b < 512)       { src = b_primal; dst = APc; off = b; }
    else if (b < 1024) { src = W0; dst = W0c; off = b - 512; }
    else if (b < 2048) { src = W1; dst = W1c; off = b - 1024; }
    else if (b < 2304) { src = W2; dst = W2c; off = b - 2048; }
    else if (b < 2368) { src = Wz; dst = WzG; off = b - 2304; }
    else               { src = Am; dst = AG;  off = b - 2368; }
    int idx = off * 1024 + tid * 4;
    float4 v = *(const float4*)(src + idx);
    ushort4 o;
    o.x = f2bf(v.x); o.y = f2bf(v.y); o.z = f2bf(v.z); o.w = f2bf(v.w);
    *(ushort4*)(dst + idx) = o;
}

// fragment read from a 32x128 bf16 tile with 4-bit XOR granule swizzle
__device__ __forceinline__ bf16x8 frag128(const unsigned short* lds, int row, int gc) {
    int phys = gc ^ (row & 15);
    return __builtin_bit_cast(bf16x8, *(const uint4*)(lds + row * 128 + phys * 8));
}

// ---- 32x32-tile MFMA GEMM, BK=128, double-buffered, 4 blocks/CU ----
// C[M,N] = act(A[M,K] @ B[N,K]^T + bias)
template<int K, int NTN, bool RELU, bool F32OUT>
__global__ __launch_bounds__(256, 4) void gemm32_k(
    const unsigned short* __restrict__ A,   // [M][K] bf16
    const unsigned short* __restrict__ B,   // [N][K] bf16
    const float* __restrict__ bias,         // [N]
    void* __restrict__ Cv, int N_)
{
    constexpr int NCH = K / 128;
    __shared__ __align__(16) unsigned short As[2][32 * 128];
    __shared__ __align__(16) unsigned short Bs[2][32 * 128];

    const int tid = threadIdx.x;
    const int w = tid >> 6;
    const int lane = tid & 63;
    const int ln = lane & 15;
    const int q  = lane >> 4;
    const int wr = w >> 1;
    const int wc = w & 1;
    const int row0 = (blockIdx.x / NTN) * 32;
    const int col0 = (blockIdx.x % NTN) * 32;
    const unsigned short* Ab = A + row0 * K;
    const unsigned short* Bb = B + col0 * K;

    // staging: 512 granules (16B) per matrix per buffer; wave w stages 128 (2 instrs)
    int soff[2], dbase[2];
#pragma unroll
    for (int i = 0; i < 2; ++i) {
        int P = w * 128 + i * 64 + lane;       // LDS granule (lane-linear, wave-uniform base)
        int row = P >> 4, pgc = P & 15;
        soff[i]  = row * K + (pgc ^ (row & 15)) * 8;   // XOR-permuted global source
        dbase[i] = (w * 128 + i * 64) * 8;             // shorts
    }

    f32x4 acc = {0.f, 0.f, 0.f, 0.f};

    // prologue: stage chunk 0 into buffer 0
#pragma unroll
    for (int i = 0; i < 2; ++i) {
        gload_lds16(Ab + soff[i], &As[0][dbase[i]]);
        gload_lds16(Bb + soff[i], &Bs[0][dbase[i]]);
    }

    for (int c = 0; c < NCH; ++c) {
        __syncthreads();                       // buf[c&1] loads drained (vmcnt 0)
        if (c + 1 < NCH) {                     // prefetch next chunk into other buffer
            const unsigned short* Ak = Ab + (c + 1) * 128;
            const unsigned short* Bk = Bb + (c + 1) * 128;
            int nb = (c + 1) & 1;
#pragma unroll
            for (int i = 0; i < 2; ++i) {
                gload_lds16(Ak + soff[i], &As[nb][dbase[i]]);
                gload_lds16(Bk + soff[i], &Bs[nb][dbase[i]]);
            }
        }
        const unsigned short* Ac = As[c & 1];
        const unsigned short* Bc = Bs[c & 1];
#pragma unroll
        for (int ks = 0; ks < 4; ++ks) {
            bf16x8 af = frag128(Ac, wr * 16 + ln, ks * 4 + q);
            bf16x8 bf = frag128(Bc, wc * 16 + ln, ks * 4 + q);
            acc = __builtin_amdgcn_mfma_f32_16x16x32_bf16(af, bf, acc, 0, 0, 0);
        }
    }

    const int c = col0 + wc * 16 + ln;
    const float bv = bias[c];
#pragma unroll
    for (int i = 0; i < 4; ++i) {
        int r = row0 + wr * 16 + q * 4 + i;
        float v = acc[i] + bv;
        if (RELU) v = fmaxf(v, 0.0f);
        if (F32OUT) ((float*)Cv)[r * N_ + c] = v;
        else ((unsigned short*)Cv)[r * N_ + c] = f2bf(v);
    }
}

// ---- 20-iter fixed-point loop; Wz/A fragments register-resident; 64 blocks ----
__global__ __launch_bounds__(256, 1) void loop_k(
    const float* __restrict__ b_vec, float* __restrict__ out,
    float* __restrict__ ws)
{
    __shared__ __align__(16) unsigned char smem[16 * 264 * 2 + 256];
    unsigned int* res = (unsigned int*)(ws + WS_RES);
    float* bp = ws + WS_BP;
    const unsigned short* WzG = (const unsigned short*)(ws + WS_WZG);
    const unsigned short* AG  = (const unsigned short*)(ws + WS_AG);
    float* outz = out + BSZ * OUT_DIM;

    const int tid  = threadIdx.x;
    const int wave = tid >> 6;
    const int lane = tid & 63;
    const int ln   = lane & 15;
    const int q    = lane >> 4;
    const int r0   = blockIdx.x * 16;

    unsigned short (*zS)[264] = (unsigned short(*)[264])smem;
    float* red = (float*)(smem + 16 * 264 * 2);

    {
        int row = tid >> 4;
        int c0  = (tid & 15) * 16;
        const float* src = outz + (r0 + row) * OUT_DIM + c0;
#pragma unroll
        for (int i = 0; i < 16; ++i) zS[row][c0 + i] = f2bf(src[i]);
    }

    bf16x8 afr[2][8];
    float bvv[2];
#pragma unroll
    for (int mt = 0; mt < 2; ++mt) {
        int m = wave * 32 + mt * 16 + ln;
        bvv[mt] = b_vec[m];
#pragma unroll
        for (int ks = 0; ks < 8; ++ks)
            afr[mt][ks] = __builtin_bit_cast(bf16x8, *(const uint4*)(AG + m * OUT_DIM + ks * 32 + q * 8));
    }
    int colg[4];
    float bpv[4];
    bf16x8 wzfr[4][8];
#pragma unroll
    for (int nt = 0; nt < 4; ++nt) {
        colg[nt] = wave * 64 + nt * 16 + ln;
        bpv[nt]  = bp[colg[nt]];
#pragma unroll
        for (int ks = 0; ks < 8; ++ks)
            wzfr[nt][ks] = __builtin_bit_cast(bf16x8, *(const uint4*)(WzG + colg[nt] * OUT_DIM + ks * 32 + q * 8));
    }
    __syncthreads();

    bf16x8 zfr[8];
#pragma unroll
    for (int ks = 0; ks < 8; ++ks)
        zfr[ks] = __builtin_bit_cast(bf16x8, *(const uint4*)&zS[ln][ks * 32 + q * 8]);

    const f32x4 zero4 = {0.f, 0.f, 0.f, 0.f};

    for (int t = 1; t <= MAX_ITER_N; ++t) {
        f32x4 acc[4];
#pragma unroll
        for (int nt = 0; nt < 4; ++nt) acc[nt] = zero4;
#pragma unroll
        for (int ks = 0; ks < 8; ++ks)
#pragma unroll
            for (int nt = 0; nt < 4; ++nt)
                acc[nt] = __builtin_amdgcn_mfma_f32_16x16x32_bf16(zfr[ks], wzfr[nt][ks], acc[nt], 0, 0, 0);
        float vals[4][4];
#pragma unroll
        for (int nt = 0; nt < 4; ++nt)
#pragma unroll
            for (int i = 0; i < 4; ++i) {
                float v = acc[nt][i] + bpv[nt];
                if (colg[nt] >= FREE_NUM_N) v = fmaxf(v, 0.0f);
                vals[nt][i] = v;
            }
        if (t == MAX_ITER_N) {
#pragma unroll
            for (int nt = 0; nt < 4; ++nt)
#pragma unroll
                for (int i = 0; i < 4; ++i)
                    out[(r0 + q * 4 + i) * OUT_DIM + colg[nt]] = vals[nt][i];
        }
        __syncthreads();   // S1: all waves done reading zS (z_{t-1})
#pragma unroll
        for (int nt = 0; nt < 4; ++nt)
#pragma unroll
            for (int i = 0; i < 4; ++i)
                zS[q * 4 + i][colg[nt]] = f2bf(vals[nt][i]);
        __syncthreads();   // S2: zS = z_t complete
#pragma unroll
        for (int ks = 0; ks < 8; ++ks)
            zfr[ks] = __builtin_bit_cast(bf16x8, *(const uint4*)&zS[ln][ks * 32 + q * 8]);

        f32x4 acc2[2];
        acc2[0] = zero4; acc2[1] = zero4;
#pragma unroll
        for (int ks = 0; ks < 8; ++ks)
#pragma unroll
            for (int mt = 0; mt < 2; ++mt)
                acc2[mt] = __builtin_amdgcn_mfma_f32_16x16x32_bf16(zfr[ks], afr[mt][ks], acc2[mt], 0, 0, 0);
        float lmax = 0.0f;
#pragma unroll
        for (int mt = 0; mt < 2; ++mt)
#pragma unroll
            for (int i = 0; i < 4; ++i)
                lmax = fmaxf(lmax, fabsf(acc2[mt][i] - bvv[mt]));
#pragma unroll
        for (int off = 32; off > 0; off >>= 1)
            lmax = fmaxf(lmax, __shfl_xor(lmax, off));
        if (lane == 0) red[wave] = lmax;
        __syncthreads();   // S3
        if (tid == 0) {
            float bm = fmaxf(fmaxf(red[0], red[1]), fmaxf(red[2], red[3]));
            atomicMax(res + (t - 1), __float_as_uint(bm));
        }
    }
}

// ---- decide (replay reference stopping rule) + cold fp32 fallback; 64 blocks ----
__global__ __launch_bounds__(256) void decide_fb_k(
    const float* __restrict__ WzProj, float* __restrict__ out,
    float* __restrict__ ws)
{
    __shared__ float zF[16][257];
    unsigned int* res = (unsigned int*)(ws + WS_RES);
    float* bp = ws + WS_BP;
    float* outz = out + BSZ * OUT_DIM;
    const int tid = threadIdx.x;

    int T = MAX_ITER_N;
    for (int t = 0; t < MAX_ITER_N; ++t) {
        float r = __uint_as_float(res[t]);
        if (!(r > F_TOL_F)) { T = t + 1; break; }   // covers res<=tol and NaN
    }
    if (blockIdx.x == 0 && tid == 0)
        out[2 * BSZ * OUT_DIM] = (float)(T + 1);    // curr_iter

    if (T >= MAX_ITER_N) return;                    // hot path: nothing else to do

    const int r0 = blockIdx.x * 16;
    const int row = tid >> 4;
    const int c0 = (tid & 15) * 16;
    for (int i = 0; i < 16; ++i) zF[row][c0 + i] = outz[(r0 + row) * OUT_DIM + c0 + i];
    __syncthreads();
    const int j = tid;
    const float bj = bp[j];
    for (int t = 0; t < T; ++t) {
        float acc[16] = {};
        for (int k = 0; k < OUT_DIM; ++k) {
            float w = WzProj[j * OUT_DIM + k];
#pragma unroll
            for (int r = 0; r < 16; ++r) acc[r] += zF[r][k] * w;
        }
        __syncthreads();
#pragma unroll
        for (int r = 0; r < 16; ++r) {
            float v = acc[r] + bj;
            if (j >= FREE_NUM_N) v = fmaxf(v, 0.0f);
            zF[r][j] = v;
        }
        __syncthreads();
    }
    for (int i = 0; i < 16; ++i) out[(r0 + row) * OUT_DIM + c0 + i] = zF[row][c0 + i];
}

extern "C" void kernel_launch(void* const* d_in, const int* in_sizes, int n_in,
                              void* d_out, int out_size, void* d_ws, size_t ws_size,
                              hipStream_t stream) {
    const float* b_primal = (const float*)d_in[0];
    const float* W0     = (const float*)d_in[1];
    const float* b0     = (const float*)d_in[2];
    const float* W1     = (const float*)d_in[3];
    const float* b1     = (const float*)d_in[4];
    const float* W2     = (const float*)d_in[5];
    const float* b2     = (const float*)d_in[6];
    const float* Amat   = (const float*)d_in[7];
    const float* b_vec  = (const float*)d_in[8];
    const float* WzProj = (const float*)d_in[9];
    const float* WbProj = (const float*)d_in[10];
    float* out = (float*)d_out;
    float* ws  = (float*)d_ws;

    unsigned short* h1c = (unsigned short*)(ws + WS_H1);
    unsigned short* h2c = (unsigned short*)(ws + WS_H2);
    unsigned short* APc = (unsigned short*)(ws + WS_APC);
    unsigned short* W0c = (unsigned short*)(ws + WS_W0C);
    unsigned short* W1c = (unsigned short*)(ws + WS_W1C);
    unsigned short* W2c = (unsigned short*)(ws + WS_W2C);
    float* outz = out + BSZ * OUT_DIM;

    // zero res slots (ws is poisoned 0xAA before every call)
    hipMemsetAsync(ws, 0, WS_BP * sizeof(float), stream);

    hipLaunchKernelGGL(prep_k, dim3(2401), dim3(256), 0, stream,
                       b_primal, W0, W1, W2, WzProj, Amat, b_vec, WbProj, ws);

    hipLaunchKernelGGL((gemm32_k<IN_DIM, 32, true, false>), dim3(1024), dim3(256), 0, stream,
                       APc, W0c, b0, (void*)h1c, HID);
    hipLaunchKernelGGL((gemm32_k<HID, 32, true, false>), dim3(1024), dim3(256), 0, stream,
                       h1c, W1c, b1, (void*)h2c, HID);
    hipLaunchKernelGGL((gemm32_k<HID, 8, false, true>), dim3(256), dim3(256), 0, stream,
                       h2c, W2c, b2, (void*)outz, OUT_DIM);

    hipLaunchKernelGGL(loop_k, dim3(64), dim3(256), 0, stream, b_vec, out, ws);
    hipLaunchKernelGGL(decide_fb_k, dim3(64), dim3(256), 0, stream, WzProj, out, ws);
}